// Round 6
// baseline (123.197 us; speedup 1.0000x reference)
//
#include <hip/hip_runtime.h>

#define N 32768
#define P 8192
#define NBLK (N / 32)            // 1024 blocks; 32 x's per block (one MFMA col-tile)
#define THREADS 512              // 8 waves = 8 P-slices
#define SLICES 8
#define PT (P / 32)              // 256 pattern-tiles of 32
#define TPW (PT / SLICES)        // 32 tiles per wave

// f = log2(e)/(2*sigma^2), sigma^2 = 1.44; per-x |x|^2 cancels in num/den.
#define RBF_F 0.50093577808645257f

typedef float  v2f    __attribute__((ext_vector_type(2)));
typedef float  f32x4  __attribute__((ext_vector_type(4)));
typedef float  f32x16 __attribute__((ext_vector_type(16)));
typedef short  s16x8  __attribute__((ext_vector_type(8)));

static __device__ __forceinline__ float fast_exp2(float x) {
#if __has_builtin(__builtin_amdgcn_exp2f)
    return __builtin_amdgcn_exp2f(x);
#else
    return exp2f(x);
#endif
}

static __device__ __forceinline__ unsigned short f2bf(float f) {   // RN f32->bf16
    unsigned u = __float_as_uint(f);
    u += 0x7FFF + ((u >> 16) & 1);
    return (unsigned short)(u >> 16);
}
static __device__ __forceinline__ float bf2f(unsigned short h) {
    return __uint_as_float((unsigned)h << 16);
}

// Per pattern p: A-frag slots (hi/lo split of 2f*p, pre-scaled x0.5 for the
// duplicate-K-group trick) + weights e2c2=2^(-f|p|^2), w'=w*e2c2 stored in
// D-fragment row order: row(r,g) = (r&3) + 8*(r>>2) + 4*g  (m74/m101 layout).
__global__ void prep_kernel(const float* __restrict__ pat,
                            const float* __restrict__ w2,
                            s16x8* __restrict__ afrag,   // [P]   16 B each
                            float* __restrict__ wperm,   // [PT*2*16]
                            float* __restrict__ eperm) { // [PT*2*16]
    int p = blockIdx.x * blockDim.x + threadIdx.x;
    if (p >= P) return;
    float p0 = pat[2 * p], p1 = pat[2 * p + 1];
    float P0 = 2.0f * RBF_F * p0, P1 = 2.0f * RBF_F * p1;
    unsigned short h0 = f2bf(P0);
    unsigned short l0 = f2bf(P0 - bf2f(h0));
    unsigned short h1 = f2bf(P1);
    unsigned short l1 = f2bf(P1 - bf2f(h1));
    // exact halve (exponent decrement via re-round of value*0.5)
    unsigned short H0 = f2bf(bf2f(h0) * 0.5f), L0 = f2bf(bf2f(l0) * 0.5f);
    unsigned short H1 = f2bf(bf2f(h1) * 0.5f), L1 = f2bf(bf2f(l1) * 0.5f);
    // pairs with B(x) slots [xh0, xl0, xh0, xh1, xl1, xh1, 0, 0]:
    //   hi*hi + hi*lo + lo*hi per component
    s16x8 a;
    a[0] = (short)H0; a[1] = (short)H0; a[2] = (short)L0;
    a[3] = (short)H1; a[4] = (short)H1; a[5] = (short)L1;
    a[6] = 0;         a[7] = 0;
    int tile = p >> 5, row = p & 31;
    afrag[tile * 32 + row] = a;

    float c2 = -RBF_F * (p0 * p0 + p1 * p1);
    float e  = exp2f(c2);
    float wp = w2[p] * e;
    int g = (row >> 2) & 1;
    int r = (row & 3) | (((row >> 3) & 3) << 2);
    wperm[(tile * 2 + g) * 16 + r] = wp;
    eperm[(tile * 2 + g) * 16 + r] = e;
}

#define MFMA(A, B, C) __builtin_amdgcn_mfma_f32_32x32x16_bf16((A), (B), (C), 0, 0, 0)

// accumulate 4 k's (D[base..base+3]) against weight quads Wq/Eq via pk_fma
#define ACC4(D, Wq, Eq, base)                                                 \
    den2 = __builtin_elementwise_fma((v2f){(D)[base], (D)[base + 1]},         \
             (v2f){(Eq)[0], (Eq)[1]}, den2);                                  \
    num2 = __builtin_elementwise_fma((v2f){(D)[base], (D)[base + 1]},         \
             (v2f){(Wq)[0], (Wq)[1]}, num2);                                  \
    den2 = __builtin_elementwise_fma((v2f){(D)[base + 2], (D)[base + 3]},     \
             (v2f){(Eq)[2], (Eq)[3]}, den2);                                  \
    num2 = __builtin_elementwise_fma((v2f){(D)[base + 2], (D)[base + 3]},     \
             (v2f){(Wq)[2], (Wq)[3]}, num2);

__global__ __launch_bounds__(THREADS, 4) void
rbf_kernel(const float* __restrict__ X,
           const s16x8* __restrict__ afrag,
           const f32x4* __restrict__ wperm4,
           const f32x4* __restrict__ eperm4,
           float* __restrict__ out) {
    const int t    = threadIdx.x;
    const int lane = t & 63;
    const int wv   = __builtin_amdgcn_readfirstlane(t >> 6);  // slice 0..7
    const int col  = lane & 31;
    const int g    = lane >> 5;

    // B operand (x side), built once: col-th x of this block's 32-x tile
    float2 xv = ((const float2*)X)[blockIdx.x * 32 + col];
    unsigned short xh0 = f2bf(xv.x), xl0 = f2bf(xv.x - bf2f(xh0));
    unsigned short xh1 = f2bf(xv.y), xl1 = f2bf(xv.y - bf2f(xh1));
    s16x8 bx;
    bx[0] = (short)xh0; bx[1] = (short)xl0; bx[2] = (short)xh0;
    bx[3] = (short)xh1; bx[4] = (short)xl1; bx[5] = (short)xh1;
    bx[6] = 0;          bx[7] = 0;

    f32x16 Z;
#pragma unroll
    for (int i = 0; i < 16; ++i) Z[i] = 0.0f;

    const int tile0 = wv * TPW;
    const s16x8* __restrict__ Ap = afrag + tile0 * 32 + col;       // +32/tile
    const f32x4* __restrict__ Wp = wperm4 + (tile0 * 2 + g) * 4;   // +8/tile
    const f32x4* __restrict__ Ep = eperm4 + (tile0 * 2 + g) * 4;

    // prologue
    s16x8 Af0 = Ap[0];
    s16x8 Af1 = Ap[32];
    f32x16 D0 = MFMA(Af0, bx, Z);   // tile 0
    f32x16 D1;

    v2f num2 = (v2f){0.f, 0.f}, den2 = (v2f){0.f, 0.f};

    for (int tt = 0; tt < TPW; tt += 2) {
        // ---- half A: D0 holds tile tt ----
        D1 = MFMA(Af1, bx, Z);                        // start tile tt+1
        Af0 = Ap[((tt + 2) & (TPW - 1)) * 32];        // refill frag (wrap)
        f32x4 Wa0 = Wp[tt * 8 + 0], Wa1 = Wp[tt * 8 + 1];
        f32x4 Wa2 = Wp[tt * 8 + 2], Wa3 = Wp[tt * 8 + 3];
        f32x4 Ea0 = Ep[tt * 8 + 0], Ea1 = Ep[tt * 8 + 1];
        f32x4 Ea2 = Ep[tt * 8 + 2], Ea3 = Ep[tt * 8 + 3];
#pragma unroll
        for (int i = 0; i < 16; ++i) D0[i] = fast_exp2(D0[i]);
        ACC4(D0, Wa0, Ea0, 0)
        ACC4(D0, Wa1, Ea1, 4)
        ACC4(D0, Wa2, Ea2, 8)
        ACC4(D0, Wa3, Ea3, 12)
        // ---- half B: D1 holds tile tt+1 ----
        D0 = MFMA(Af0, bx, Z);                        // start tile tt+2
        Af1 = Ap[((tt + 3) & (TPW - 1)) * 32];
        f32x4 Wb0 = Wp[(tt + 1) * 8 + 0], Wb1 = Wp[(tt + 1) * 8 + 1];
        f32x4 Wb2 = Wp[(tt + 1) * 8 + 2], Wb3 = Wp[(tt + 1) * 8 + 3];
        f32x4 Eb0 = Ep[(tt + 1) * 8 + 0], Eb1 = Ep[(tt + 1) * 8 + 1];
        f32x4 Eb2 = Ep[(tt + 1) * 8 + 2], Eb3 = Ep[(tt + 1) * 8 + 3];
#pragma unroll
        for (int i = 0; i < 16; ++i) D1[i] = fast_exp2(D1[i]);
        ACC4(D1, Wb0, Eb0, 0)
        ACC4(D1, Wb1, Eb1, 4)
        ACC4(D1, Wb2, Eb2, 8)
        ACC4(D1, Wb3, Eb3, 12)
    }

    // epilogue: fold pair, combine the two duplicate row-groups (lane ^ 32),
    // then combine the 8 P-slices via LDS.
    float num = num2.x + num2.y;
    float den = den2.x + den2.y;
    num += __shfl_xor(num, 32, 64);
    den += __shfl_xor(den, 32, 64);

    __shared__ float red[SLICES][32][2];
    if (lane < 32) {
        red[wv][lane][0] = num;
        red[wv][lane][1] = den;
    }
    __syncthreads();

    if (t < 32) {
        float nn = 0.f, dd = 0.f;
#pragma unroll
        for (int s = 0; s < SLICES; ++s) {
            nn += red[s][t][0];
            dd += red[s][t][1];
        }
        out[blockIdx.x * 32 + t] = nn / dd;
    }
}

extern "C" void kernel_launch(void* const* d_in, const int* in_sizes, int n_in,
                              void* d_out, int out_size, void* d_ws, size_t ws_size,
                              hipStream_t stream) {
    const float* X   = (const float*)d_in[0];   // [32768, 2]
    const float* pat = (const float*)d_in[1];   // [8192, 2]
    const float* w2  = (const float*)d_in[2];   // [8192]
    float* out = (float*)d_out;                 // [32768]

    char* ws = (char*)d_ws;                     // 192 KB used
    s16x8* afrag = (s16x8*)ws;                              // 128 KB
    float* wperm = (float*)(ws + (size_t)P * 16);           // 32 KB
    float* eperm = (float*)(ws + (size_t)P * 16 + (size_t)PT * 2 * 16 * 4);

    prep_kernel<<<(P + 255) / 256, 256, 0, stream>>>(pat, w2, afrag, wperm, eperm);
    rbf_kernel<<<NBLK, THREADS, 0, stream>>>(X, afrag,
                                             (const f32x4*)wperm,
                                             (const f32x4*)eperm, out);
}